// Round 8
// baseline (168.493 us; speedup 1.0000x reference)
//
#include <hip/hip_runtime.h>
#include <float.h>
#include <stdint.h>

#define HH 128
#define NROWS 32768
#define KCODES 4096
#define CAPR 40

typedef _Float16 half8 __attribute__((ext_vector_type(8)));
typedef _Float16 half4_t __attribute__((ext_vector_type(4)));
typedef float floatx4 __attribute__((ext_vector_type(4)));
typedef float floatx16 __attribute__((ext_vector_type(16)));

// order-preserving float<->uint key (handles negatives) for LDS atomicMin
__device__ __forceinline__ unsigned fkey(float f) {
    unsigned b = __float_as_uint(f);
    return b ^ ((unsigned)((int)b >> 31) | 0x80000000u);
}
__device__ __forceinline__ float funkey(unsigned k) {
    unsigned b = (k & 0x80000000u) ? (k ^ 0x80000000u) : ~k;
    return __uint_as_float(b);
}

// ---------------------------------------------------------------------------
// ws layout (bytes): 0 wq2R float[4096] (0.5*||w||^2 in MFMA C-register
// order) | 16384 whPart float[256] | 17408 whiA ushort[524288] (1 MB,
// A-frag order). whiA: chunk (cb = code>>5, s = h/16) = 512 ushorts; entry
// lane = kh*32 + (code&31) holds w_hi[code][s*16 + kh*8 .. +8] (round-0
// validated). wq2R[cb*32 + kh*16 + r] = 0.5*||w||^2 of code
// cb*32+(r&3)+8*(r>>2)+4*kh (m74/m101 C/D layout).
// ---------------------------------------------------------------------------

__global__ __launch_bounds__(256) void vq_prep(const float* __restrict__ w,
        float* __restrict__ wq2R, ushort* __restrict__ whiA,
        float* __restrict__ whPart, float* __restrict__ loss_slot) {
    __shared__ float sWH[16];
    const int t = threadIdx.x;
    const int tid = blockIdx.x * 256 + t;
    if (tid == 0) loss_slot[0] = 0.0f;   // d_out poisoned 0xAA each launch
    const int c = tid >> 4, hg = tid & 15, s = hg >> 1, khh = hg & 1;

    const float4* src = reinterpret_cast<const float4*>(w + (size_t)c * HH + (hg << 3));
    float4 a = src[0], b = src[1];
    _Float16 h0=(_Float16)a.x, h1=(_Float16)a.y, h2=(_Float16)a.z, h3=(_Float16)a.w;
    _Float16 h4=(_Float16)b.x, h5=(_Float16)b.y, h6=(_Float16)b.z, h7=(_Float16)b.w;
    half8 hi = {h0, h1, h2, h3, h4, h5, h6, h7};
    *reinterpret_cast<half8*>(&whiA[((size_t)(c >> 5) * 8 + s) * 512 +
                                    (((khh << 5) | (c & 31)) << 3)]) = hi;

    float ssq = 0.f;
    ssq = fmaf(a.x, a.x, ssq); ssq = fmaf(a.y, a.y, ssq);
    ssq = fmaf(a.z, a.z, ssq); ssq = fmaf(a.w, a.w, ssq);
    ssq = fmaf(b.x, b.x, ssq); ssq = fmaf(b.y, b.y, ssq);
    ssq = fmaf(b.z, b.z, ssq); ssq = fmaf(b.w, b.w, ssq);
    ssq += __shfl_xor(ssq, 1, 64);
    ssq += __shfl_xor(ssq, 2, 64);
    ssq += __shfl_xor(ssq, 4, 64);
    ssq += __shfl_xor(ssq, 8, 64);
    if (hg == 0) {
        int co = c & 31;
        wq2R[((c >> 5) << 5) + (((co >> 2) & 1) << 4) + ((co & 3) | ((co >> 3) << 2))]
            = 0.5f * ssq;
        sWH[t >> 4] = ssq;
    }
    __syncthreads();
    if (t == 0) {
        float mh = 0.f;
#pragma unroll
        for (int i = 0; i < 16; ++i) mh = fmaxf(mh, sWH[i]);
        whPart[blockIdx.x] = mh;
    }
}

// ---------------------------------------------------------------------------
// Fused scan, 4 row-groups per wave: 128 rows/block, 256 threads / 4 waves,
// each wave scans a 1024-code quarter against FOUR B-row-sets -> 32 MFMA
// per body as 4 independent 8-chains. Body compute (~500cy) now exceeds the
// prefetch L2 latency, so loads self-hide via ILP/MLP with NO barriers.
// Rationale (r3 vs r6 A/B): MFMA-work-per-A-load is the only lever that has
// paid; TLP (r6), LDS A-sharing (r7), wide blocks (r4/r5) all failed.
// launch_bounds(256,1): ~300 VGPR working set needs the 512 budget (1
// wave/SIMD, 1 block/CU, grid=256). Low occupancy is BY DESIGN here.
// ---------------------------------------------------------------------------
__global__ __launch_bounds__(256, 1) void vq_fused(
        const float* __restrict__ z, const float* __restrict__ w,
        const float* __restrict__ wq2R, const ushort* __restrict__ whiA,
        const float* __restrict__ whPart,
        float* __restrict__ out_zq, float* __restrict__ out_idx,
        float* __restrict__ out_loss) {
    __shared__ unsigned smin[128];
    __shared__ int rowcnt[128];
    __shared__ int rowovf[128];
    __shared__ int rowlist[128 * CAPR];
    __shared__ float swh[4];
    __shared__ int fb[128];
    __shared__ float lred[4];
    __shared__ __align__(16) float swq[KCODES];   // 16 KB wq2R copy

    const int t = threadIdx.x;
    const int lane = t & 63, wid = t >> 6;
    const int n = lane & 31, kh = lane >> 5;
    const int rowBase = blockIdx.x * 128;

    // codebook max ||w||^2 partial reduce (256 partials from prep)
    float wp = whPart[t];
#pragma unroll
    for (int off = 1; off < 64; off <<= 1) wp = fmaxf(wp, __shfl_xor(wp, off, 64));
    if (lane == 0) swh[wid] = wp;
    if (t < 128) { smin[t] = 0xFFFFFFFFu; rowcnt[t] = 0; rowovf[t] = 0; }

    // stage wq2R into LDS (scan C-init reads become broadcast ds_reads)
    {
        const float4* g4 = reinterpret_cast<const float4*>(wq2R);
        float4* s4 = reinterpret_cast<float4*>(swq);
#pragma unroll
        for (int i = 0; i < 4; ++i) s4[i * 256 + t] = g4[i * 256 + t];
    }

    // ---- stage z: NEGATED hi fp16 B-frags for 4 row-groups + norms ----
    half8 zb0[8], zb1[8], zb2[8], zb3[8];
    float zn0 = 0.f, zl0 = 0.f, zn1 = 0.f, zl1 = 0.f;
    float zn2g = 0.f, zl2g = 0.f, zn3 = 0.f, zl3 = 0.f;

    auto stageZ = [&](int rgb, half8 (&zbx)[8], float& zn2, float& zl2) {
        const float* zr = z + (size_t)(rowBase + rgb + n) * HH + (kh << 3);
#pragma unroll
        for (int s = 0; s < 8; ++s) {
            float4 a = *reinterpret_cast<const float4*>(zr + (s << 4));
            float4 b = *reinterpret_cast<const float4*>(zr + (s << 4) + 4);
            _Float16 h0=(_Float16)a.x, h1=(_Float16)a.y, h2=(_Float16)a.z, h3=(_Float16)a.w;
            _Float16 h4=(_Float16)b.x, h5=(_Float16)b.y, h6=(_Float16)b.z, h7=(_Float16)b.w;
            zbx[s] = (half8){-h0, -h1, -h2, -h3, -h4, -h5, -h6, -h7};
            zn2 = fmaf(a.x,a.x,zn2); zn2 = fmaf(a.y,a.y,zn2);
            zn2 = fmaf(a.z,a.z,zn2); zn2 = fmaf(a.w,a.w,zn2);
            zn2 = fmaf(b.x,b.x,zn2); zn2 = fmaf(b.y,b.y,zn2);
            zn2 = fmaf(b.z,b.z,zn2); zn2 = fmaf(b.w,b.w,zn2);
            float l0=a.x-(float)h0, l1=a.y-(float)h1, l2=a.z-(float)h2, l3=a.w-(float)h3;
            float l4=b.x-(float)h4, l5=b.y-(float)h5, l6=b.z-(float)h6, l7=b.w-(float)h7;
            zl2 = fmaf(l0,l0,zl2); zl2 = fmaf(l1,l1,zl2);
            zl2 = fmaf(l2,l2,zl2); zl2 = fmaf(l3,l3,zl2);
            zl2 = fmaf(l4,l4,zl2); zl2 = fmaf(l5,l5,zl2);
            zl2 = fmaf(l6,l6,zl2); zl2 = fmaf(l7,l7,zl2);
        }
        zn2 += __shfl_xor(zn2, 32, 64);
        zl2 += __shfl_xor(zl2, 32, 64);
    };
    stageZ(0,  zb0, zn0,  zl0);
    stageZ(32, zb1, zn1,  zl1);
    stageZ(64, zb2, zn2g, zl2g);
    stageZ(96, zb3, zn3,  zl3);

    __syncthreads();   // smin/cnt init + swh + swq visible

    // rigorous window: |d/2_true - sc| <= E; accept if sc < runmin + thrw,
    // thrw > 2E  =>  true argmin always collected; non-collected strictly worse
    float WH = sqrtf(fmaxf(fmaxf(swh[0], swh[1]), fmaxf(swh[2], swh[3])));
    auto mkthr = [&](float zn2, float zl2) {
        float znr = sqrtf(zn2), zlr = sqrtf(zl2);
        float E = zlr * WH * 1.01f + (znr + zlr) * (WH * 4.8828125e-4f + 1e-6f) + 4e-3f;
        return 2.0f * E * 1.05f + 0.01f;
    };
    const float thrw0 = mkthr(zn0, zl0),  thrw1 = mkthr(zn1, zl1);
    const float thrw2 = mkthr(zn2g, zl2g), thrw3 = mkthr(zn3, zl3);

    const half8* A8 = reinterpret_cast<const half8*>(whiA);
    const int cb0 = wid << 5;
    float m10 = FLT_MAX, m1p0 = FLT_MAX, m11 = FLT_MAX, m1p1 = FLT_MAX;
    float m12 = FLT_MAX, m1p2 = FLT_MAX, m13 = FLT_MAX, m1p3 = FLT_MAX;

    half8 afA[8], afB[8];
    {
        const half8* ap = A8 + ((size_t)cb0 << 3) * 64 + lane;
#pragma unroll
        for (int p = 0; p < 8; ++p) afA[p] = ap[p * 64];
    }

    // per-row-group scan epilogue: min-tree, bound check, rare collection
    auto proc = [&](int it, int cb, const floatx16& acc, float& m1, float& m1pub,
                    float thrw, int row) {
        float t00=fminf(acc[0],acc[1]),   t01=fminf(acc[2],acc[3]);
        float t02=fminf(acc[4],acc[5]),   t03=fminf(acc[6],acc[7]);
        float t04=fminf(acc[8],acc[9]),   t05=fminf(acc[10],acc[11]);
        float t06=fminf(acc[12],acc[13]), t07=fminf(acc[14],acc[15]);
        float tmin = fminf(fminf(fminf(t00,t01), fminf(t02,t03)),
                           fminf(fminf(t04,t05), fminf(t06,t07)));
        m1 = fminf(m1, tmin);
        if (m1 < m1pub) { atomicMin(&smin[row], fkey(m1)); m1pub = m1; }
        // register-only pre-check: shared bound <= local bound, so a local
        // fail proves no candidate here (m1 already includes this tile)
        if (it > 0 && tmin < m1 + thrw) {
            float sh = funkey(((volatile unsigned*)smin)[row]);
            float bound = fminf(sh, m1) + thrw;
            if (tmin < bound) {
                unsigned cm = 0;
#pragma unroll
                for (int r = 0; r < 16; ++r)
                    if (acc[r] < bound) cm |= (1u << r);
                int cc = __popc(cm);
                int ix = atomicAdd(&rowcnt[row], cc);
                if (ix + cc > CAPR) rowovf[row] = 1;
#pragma unroll
                for (int r = 0; r < 16; ++r) {
                    if (cm & (1u << r)) {
                        if (ix < CAPR)
                            rowlist[row * CAPR + ix] =
                                (cb << 5) + (r & 3) + ((r >> 2) << 3) + (kh << 2);
                        ++ix;
                    }
                }
            }
        }
    };

    auto body = [&](int it, half8 (&cur)[8], half8 (&nxt)[8]) {
        const int cb = cb0 + ((it < 32) ? it : 0);
        if (it < 32) {
            const int cbn = cb0 + ((it + 1) & 31);
            const half8* ap = A8 + ((size_t)cbn << 3) * 64 + lane;
#pragma unroll
            for (int p = 0; p < 8; ++p) nxt[p] = ap[p * 64];
        }
        // C-init from LDS wq2 (broadcast, conflict-free): acc = d/2 estimate
        floatx16 wqc = *reinterpret_cast<const floatx16*>(&swq[(cb << 5) + (kh << 4)]);
        floatx16 a0 = __builtin_amdgcn_mfma_f32_32x32x16_f16(cur[0], zb0[0], wqc, 0, 0, 0);
        floatx16 a1 = __builtin_amdgcn_mfma_f32_32x32x16_f16(cur[0], zb1[0], wqc, 0, 0, 0);
        floatx16 a2 = __builtin_amdgcn_mfma_f32_32x32x16_f16(cur[0], zb2[0], wqc, 0, 0, 0);
        floatx16 a3 = __builtin_amdgcn_mfma_f32_32x32x16_f16(cur[0], zb3[0], wqc, 0, 0, 0);
#pragma unroll
        for (int s = 1; s < 8; ++s) {
            a0 = __builtin_amdgcn_mfma_f32_32x32x16_f16(cur[s], zb0[s], a0, 0, 0, 0);
            a1 = __builtin_amdgcn_mfma_f32_32x32x16_f16(cur[s], zb1[s], a1, 0, 0, 0);
            a2 = __builtin_amdgcn_mfma_f32_32x32x16_f16(cur[s], zb2[s], a2, 0, 0, 0);
            a3 = __builtin_amdgcn_mfma_f32_32x32x16_f16(cur[s], zb3[s], a3, 0, 0, 0);
        }
        proc(it, cb, a0, m10, m1p0, thrw0, n);
        proc(it, cb, a1, m11, m1p1, thrw1, n + 32);
        proc(it, cb, a2, m12, m1p2, thrw2, n + 64);
        proc(it, cb, a3, m13, m1p3, thrw3, n + 96);
    };

#pragma unroll 1
    for (int itp = 0; itp < 16; ++itp) {
        body(2 * itp,     afA, afB);
        body(2 * itp + 1, afB, afA);
    }
    body(32, afA, afB);   // re-pass tile 0 (warm bound)
    __syncthreads();

    // ---- exact fp32 eval of candidates (2 threads per row, 128 rows) ----
    {
        const int erow = t >> 1, eq = t & 1;
        int cnt = rowcnt[erow];
        bool ovf = (rowovf[erow] != 0) || (cnt > CAPR) || (cnt == 0);
        if (cnt > CAPR) cnt = CAPR;
        if (ovf) {
            if (eq == 0) rowovf[erow] = 1;
        } else {
            const float* zs = z + (size_t)(rowBase + erow) * HH + (eq << 6);
            float4 zreg[16];
#pragma unroll
            for (int i = 0; i < 16; ++i)
                zreg[i] = reinterpret_cast<const float4*>(zs)[i];
            float bd = FLT_MAX; int bc = 0x7fffffff;
            for (int j = 0; j < cnt; ++j) {
                int c = rowlist[erow * CAPR + j];
                const float* wr = w + (size_t)c * HH + (eq << 6);
                float dot = 0.f;
#pragma unroll
                for (int i = 0; i < 16; ++i) {
                    float4 wv = reinterpret_cast<const float4*>(wr)[i];
                    dot = fmaf(zreg[i].x, wv.x, dot);
                    dot = fmaf(zreg[i].y, wv.y, dot);
                    dot = fmaf(zreg[i].z, wv.z, dot);
                    dot = fmaf(zreg[i].w, wv.w, dot);
                }
                dot += __shfl_xor(dot, 1, 64);
                int co = c & 31;
                float wq2v = swq[((c >> 5) << 5) + (((co >> 2) & 1) << 4)
                                 + ((co & 3) | ((co >> 3) << 2))];
                float d2 = wq2v - dot;
                if (d2 < bd || (d2 == bd && c < bc)) { bd = d2; bc = c; }
            }
            if (eq == 0) { fb[erow] = bc; out_idx[rowBase + erow] = (float)bc; }
        }
    }
    __syncthreads();

    // ---- rigorous fallback: full exact scan for overflow rows (~never),
    // rows distributed across the 4 waves ----
    for (int rr = wid; rr < 128; rr += 4) {
        if (rowovf[rr] == 0) continue;
        const float* zrow = z + (size_t)(rowBase + rr) * HH;
        float bd = FLT_MAX; int bc = 0x7fffffff;
        for (int kq = 0; kq < 64; ++kq) {
            int c = (kq << 6) + lane;
            const float* wr = w + (size_t)c * HH;
            float dot = 0.f;
            for (int h4 = 0; h4 < 32; ++h4) {
                float4 wv = *reinterpret_cast<const float4*>(wr + (h4 << 2));
                float4 zv = *reinterpret_cast<const float4*>(zrow + (h4 << 2));
                dot = fmaf(zv.x,wv.x,dot); dot = fmaf(zv.y,wv.y,dot);
                dot = fmaf(zv.z,wv.z,dot); dot = fmaf(zv.w,wv.w,dot);
            }
            int co = c & 31;
            float wq2v = swq[((c >> 5) << 5) + (((co >> 2) & 1) << 4)
                             + ((co & 3) | ((co >> 3) << 2))];
            float d2 = wq2v - dot;
            if (d2 < bd || (d2 == bd && c < bc)) { bd = d2; bc = c; }
        }
#pragma unroll
        for (int off = 1; off < 64; off <<= 1) {
            float od = __shfl_xor(bd, off, 64);
            int oc = __shfl_xor(bc, off, 64);
            if (od < bd || (od == bd && oc < bc)) { bd = od; bc = oc; }
        }
        if (lane == 0) { fb[rr] = bc; out_idx[rowBase + rr] = (float)bc; }
    }
    __syncthreads();

    // ---- zq gather + loss (proven epilogue; 128 rows x 32 f4 / 256 thr) ----
    const float4* z4 = reinterpret_cast<const float4*>(z);
    float lsum = 0.f;
#pragma unroll
    for (int i = 0; i < 16; ++i) {
        int g = i * 256 + t;
        int r = g >> 5, f4 = g & 31;
        int code = fb[r];
        float4 wv = *reinterpret_cast<const float4*>(w + (size_t)code * HH + (f4 << 2));
        float4 zv = z4[(size_t)(rowBase + r) * 32 + f4];
        float dx = wv.x - zv.x, dy = wv.y - zv.y, dz = wv.z - zv.z, dw = wv.w - zv.w;
        lsum = fmaf(dx, dx, lsum); lsum = fmaf(dy, dy, lsum);
        lsum = fmaf(dz, dz, lsum); lsum = fmaf(dw, dw, lsum);
        *reinterpret_cast<float4*>(out_zq + (size_t)(rowBase + r) * HH + (f4 << 2)) = wv;
    }
#pragma unroll
    for (int off = 1; off < 64; off <<= 1) lsum += __shfl_xor(lsum, off, 64);
    if (lane == 0) lred[wid] = lsum;
    __syncthreads();
    if (t == 0) {
        float total = lred[0] + lred[1] + lred[2] + lred[3];
        atomicAdd(out_loss, total * (1.25f / 4194304.0f));  // (0.25+1)*mean, N*H
    }
}

// ---------------- fallback path (Round-2 kernels, proven) -------------------
__device__ __forceinline__ int plane_off_fb(int r, int hu) {
    return ((hu << 6) | (r ^ (hu & 7))) << 3;
}

__global__ __launch_bounds__(256) void vq_prep_fb(const float* __restrict__ w,
                                                  float* __restrict__ wsq,
                                                  float* __restrict__ loss_slot) {
    int c = blockIdx.x * 256 + threadIdx.x;
    if (c == 0) loss_slot[0] = 0.0f;
    if (c < KCODES) {
        const float4* row = reinterpret_cast<const float4*>(w + (size_t)c * HH);
        float s = 0.0f;
#pragma unroll
        for (int i = 0; i < HH / 4; ++i) {
            float4 v = row[i];
            s = fmaf(v.x, v.x, s); s = fmaf(v.y, v.y, s);
            s = fmaf(v.z, v.z, s); s = fmaf(v.w, v.w, s);
        }
        wsq[c] = s;
    }
}

__device__ __forceinline__ void stage_tile_fb(const float4* __restrict__ src4,
                                              ushort* lds, int hi_base, int lo_base,
                                              int t) {
#pragma unroll
    for (int p = 0; p < 8; ++p) {
        int g = p * 256 + t;
        int r = g >> 5, f4 = g & 31;
        float4 v = src4[g];
        _Float16 h0 = (_Float16)v.x, h1 = (_Float16)v.y,
                 h2 = (_Float16)v.z, h3 = (_Float16)v.w;
        half4_t hv = {h0, h1, h2, h3};
        half4_t lv = {(_Float16)(v.x - (float)h0), (_Float16)(v.y - (float)h1),
                      (_Float16)(v.z - (float)h2), (_Float16)(v.w - (float)h3)};
        int off = plane_off_fb(r, f4 >> 1) + ((f4 & 1) << 2);
        *reinterpret_cast<half4_t*>(&lds[hi_base + off]) = hv;
        *reinterpret_cast<half4_t*>(&lds[lo_base + off]) = lv;
    }
}

__global__ __launch_bounds__(256, 2) void vq_main_fb(const float* __restrict__ z,
                                                     const float* __restrict__ w,
                                                     const float* __restrict__ wsq,
                                                     float* __restrict__ out_zq,
                                                     float* __restrict__ out_idx,
                                                     float* __restrict__ out_loss) {
    __shared__ __align__(16) ushort lds[32768];
    const int t = threadIdx.x, lane = t & 63, wid = t >> 6;
    const int q = lane >> 4, m15 = lane & 15;
    const int wrow = (wid >> 1) << 5, wcol = (wid & 1) << 5;
    const int rowBase = blockIdx.x * 64;

    stage_tile_fb(reinterpret_cast<const float4*>(z + (size_t)rowBase * HH), lds, 0, 8192, t);

    float best[2][4]; int bidx[2][4];
#pragma unroll
    for (int mt = 0; mt < 2; ++mt)
#pragma unroll
        for (int rg = 0; rg < 4; ++rg) { best[mt][rg] = FLT_MAX; bidx[mt][rg] = 0; }

    const int ar0 = wrow + m15, bn0 = wcol + m15;

    for (int k0 = 0; k0 < KCODES; k0 += 64) {
        __syncthreads();
        stage_tile_fb(reinterpret_cast<const float4*>(w + (size_t)k0 * HH), lds, 16384, 24576, t);
        __syncthreads();
        floatx4 acc[2][2];
#pragma unroll
        for (int mt = 0; mt < 2; ++mt)
#pragma unroll
            for (int nt = 0; nt < 2; ++nt) acc[mt][nt] = (floatx4){0.f, 0.f, 0.f, 0.f};
#pragma unroll
        for (int c = 0; c < 4; ++c) {
            const int hu = (c << 2) + q;
            half8 zh0 = *reinterpret_cast<half8*>(&lds[plane_off_fb(ar0, hu)]);
            half8 zh1 = *reinterpret_cast<half8*>(&lds[plane_off_fb(ar0 + 16, hu)]);
            half8 zl0 = *reinterpret_cast<half8*>(&lds[8192 + plane_off_fb(ar0, hu)]);
            half8 zl1 = *reinterpret_cast<half8*>(&lds[8192 + plane_off_fb(ar0 + 16, hu)]);
            half8 wh0 = *reinterpret_cast<half8*>(&lds[16384 + plane_off_fb(bn0, hu)]);
            half8 wh1 = *reinterpret_cast<half8*>(&lds[16384 + plane_off_fb(bn0 + 16, hu)]);
            half8 wl0 = *reinterpret_cast<half8*>(&lds[24576 + plane_off_fb(bn0, hu)]);
            half8 wl1 = *reinterpret_cast<half8*>(&lds[24576 + plane_off_fb(bn0 + 16, hu)]);
            acc[0][0] = __builtin_amdgcn_mfma_f32_16x16x32_f16(zh0, wh0, acc[0][0], 0, 0, 0);
            acc[0][1] = __builtin_amdgcn_mfma_f32_16x16x32_f16(zh0, wh1, acc[0][1], 0, 0, 0);
            acc[1][0] = __builtin_amdgcn_mfma_f32_16x16x32_f16(zh1, wh0, acc[1][0], 0, 0, 0);
            acc[1][1] = __builtin_amdgcn_mfma_f32_16x16x32_f16(zh1, wh1, acc[1][1], 0, 0, 0);
            acc[0][0] = __builtin_amdgcn_mfma_f32_16x16x32_f16(zh0, wl0, acc[0][0], 0, 0, 0);
            acc[0][1] = __builtin_amdgcn_mfma_f32_16x16x32_f16(zh0, wl1, acc[0][1], 0, 0, 0);
            acc[1][0] = __builtin_amdgcn_mfma_f32_16x16x32_f16(zh1, wl0, acc[1][0], 0, 0, 0);
            acc[1][1] = __builtin_amdgcn_mfma_f32_16x16x32_f16(zh1, wl1, acc[1][1], 0, 0, 0);
            acc[0][0] = __builtin_amdgcn_mfma_f32_16x16x32_f16(zl0, wh0, acc[0][0], 0, 0, 0);
            acc[0][1] = __builtin_amdgcn_mfma_f32_16x16x32_f16(zl0, wh1, acc[0][1], 0, 0, 0);
            acc[1][0] = __builtin_amdgcn_mfma_f32_16x16x32_f16(zl1, wh0, acc[1][0], 0, 0, 0);
            acc[1][1] = __builtin_amdgcn_mfma_f32_16x16x32_f16(zl1, wh1, acc[1][1], 0, 0, 0);
        }
        float wq0 = wsq[k0 + bn0], wq1 = wsq[k0 + bn0 + 16];
#pragma unroll
        for (int mt = 0; mt < 2; ++mt)
#pragma unroll
            for (int nt = 0; nt < 2; ++nt) {
                int code = k0 + wcol + (nt << 4) + m15;
                float wqv = nt ? wq1 : wq0;
#pragma unroll
                for (int rg = 0; rg < 4; ++rg) {
                    float s = fmaf(-2.0f, acc[mt][nt][rg], wqv);
                    if (s < best[mt][rg]) { best[mt][rg] = s; bidx[mt][rg] = code; }
                }
            }
    }
#pragma unroll
    for (int off = 1; off < 16; off <<= 1)
#pragma unroll
        for (int mt = 0; mt < 2; ++mt)
#pragma unroll
            for (int rg = 0; rg < 4; ++rg) {
                float os = __shfl_xor(best[mt][rg], off, 64);
                int   oi = __shfl_xor(bidx[mt][rg], off, 64);
                if (os < best[mt][rg] || (os == best[mt][rg] && oi < bidx[mt][rg])) {
                    best[mt][rg] = os; bidx[mt][rg] = oi;
                }
            }
    float* epmin = reinterpret_cast<float*>(lds);
    int*   epidx = reinterpret_cast<int*>(reinterpret_cast<char*>(lds) + 512);
    int*   fbidx = reinterpret_cast<int*>(reinterpret_cast<char*>(lds) + 1024);
    float* lredf = reinterpret_cast<float*>(reinterpret_cast<char*>(lds) + 1280);
    __syncthreads();
    if (m15 == 0) {
        int g = wid & 1;
#pragma unroll
        for (int mt = 0; mt < 2; ++mt)
#pragma unroll
            for (int rg = 0; rg < 4; ++rg) {
                int row = wrow + (mt << 4) + (q << 2) + rg;
                epmin[g * 64 + row] = best[mt][rg];
                epidx[g * 64 + row] = bidx[mt][rg];
            }
    }
    __syncthreads();
    if (t < 64) {
        float s0 = epmin[t], s1 = epmin[64 + t];
        int   i0 = epidx[t], i1 = epidx[64 + t];
        int   fi = (s1 < s0 || (s1 == s0 && i1 < i0)) ? i1 : i0;
        fbidx[t] = fi;
        out_idx[rowBase + t] = (float)fi;
    }
    __syncthreads();
    const float4* z4 = reinterpret_cast<const float4*>(z);
    float lsum = 0.0f;
#pragma unroll
    for (int i = 0; i < 8; ++i) {
        int g = i * 256 + t;
        int r = g >> 5, f4 = g & 31;
        int code = fbidx[r];
        float4 wv = *reinterpret_cast<const float4*>(w + (size_t)code * HH + (f4 << 2));
        float4 zv = z4[(size_t)(rowBase + r) * 32 + f4];
        float dx = wv.x - zv.x, dy = wv.y - zv.y, dz = wv.z - zv.z, dw = wv.w - zv.w;
        lsum = fmaf(dx, dx, lsum); lsum = fmaf(dy, dy, lsum);
        lsum = fmaf(dz, dz, lsum); lsum = fmaf(dw, dw, lsum);
        *reinterpret_cast<float4*>(out_zq + (size_t)(rowBase + r) * HH + (f4 << 2)) = wv;
    }
#pragma unroll
    for (int off = 1; off < 64; off <<= 1) lsum += __shfl_xor(lsum, off, 64);
    if (lane == 0) lredf[wid] = lsum;
    __syncthreads();
    if (t == 0)
        atomicAdd(out_loss, (lredf[0] + lredf[1] + lredf[2] + lredf[3]) * (1.25f / 4194304.0f));
}

extern "C" void kernel_launch(void* const* d_in, const int* in_sizes, int n_in,
                              void* d_out, int out_size, void* d_ws, size_t ws_size,
                              hipStream_t stream) {
    (void)in_sizes; (void)n_in; (void)out_size;
    const float* z = (const float*)d_in[0];
    const float* w = (const float*)d_in[1];
    float* out      = (float*)d_out;
    float* out_zq   = out;
    float* out_idx  = out + (size_t)NROWS * HH;
    float* out_loss = out_idx + NROWS;

    char* wsb = (char*)d_ws;
    float*  wq2R   = (float*)(wsb + 0);        // 16 KB
    float*  whPart = (float*)(wsb + 16384);    // 1 KB
    ushort* whiA   = (ushort*)(wsb + 17408);   // 1 MB f16 codes, A-frag order
    const size_t WS_NEED = 17408 + (size_t)KCODES * HH * 2;

    if (ws_size >= WS_NEED) {
        vq_prep<<<256, 256, 0, stream>>>(w, wq2R, whiA, whPart, out_loss);
        vq_fused<<<NROWS / 128, 256, 0, stream>>>(z, w, wq2R, whiA, whPart,
                                                  out_zq, out_idx, out_loss);
    } else {
        float* wsq = (float*)d_ws;
        vq_prep_fb<<<KCODES / 256, 256, 0, stream>>>(w, wsq, out_loss);
        vq_main_fb<<<NROWS / 64, 256, 0, stream>>>(z, w, wsq, out_zq, out_idx, out_loss);
    }
}

// Round 9
// 134.079 us; speedup vs baseline: 1.2567x; 1.2567x over previous
//
#include <hip/hip_runtime.h>
#include <float.h>
#include <stdint.h>

#define HH 128
#define NROWS 32768
#define KCODES 4096
#define CAPR 40

typedef _Float16 half8 __attribute__((ext_vector_type(8)));
typedef _Float16 half4_t __attribute__((ext_vector_type(4)));
typedef float floatx4 __attribute__((ext_vector_type(4)));
typedef float floatx16 __attribute__((ext_vector_type(16)));

// order-preserving float<->uint key (handles negatives) for LDS atomicMin
__device__ __forceinline__ unsigned fkey(float f) {
    unsigned b = __float_as_uint(f);
    return b ^ ((unsigned)((int)b >> 31) | 0x80000000u);
}
__device__ __forceinline__ float funkey(unsigned k) {
    unsigned b = (k & 0x80000000u) ? (k ^ 0x80000000u) : ~k;
    return __uint_as_float(b);
}

// ---------------------------------------------------------------------------
// ws layout (bytes): 0 wq2R float[4096] (0.5*||w||^2 in MFMA C-register
// order) | 16384 whPart float[256] | 17408 whiA ushort[524288] (1 MB,
// A-frag order). whiA: chunk (cb = code>>5, s = h/16) = 512 ushorts; entry
// lane = kh*32 + (code&31) holds w_hi[code][s*16 + kh*8 .. +8] (round-0
// validated). wq2R[cb*32 + kh*16 + r] = 0.5*||w||^2 of code
// cb*32+(r&3)+8*(r>>2)+4*kh (m74/m101 C/D layout).
// ---------------------------------------------------------------------------

__global__ __launch_bounds__(256) void vq_prep(const float* __restrict__ w,
        float* __restrict__ wq2R, ushort* __restrict__ whiA,
        float* __restrict__ whPart, float* __restrict__ loss_slot) {
    __shared__ float sWH[16];
    const int t = threadIdx.x;
    const int tid = blockIdx.x * 256 + t;
    if (tid == 0) loss_slot[0] = 0.0f;   // d_out poisoned 0xAA each launch
    const int c = tid >> 4, hg = tid & 15, s = hg >> 1, khh = hg & 1;

    const float4* src = reinterpret_cast<const float4*>(w + (size_t)c * HH + (hg << 3));
    float4 a = src[0], b = src[1];
    _Float16 h0=(_Float16)a.x, h1=(_Float16)a.y, h2=(_Float16)a.z, h3=(_Float16)a.w;
    _Float16 h4=(_Float16)b.x, h5=(_Float16)b.y, h6=(_Float16)b.z, h7=(_Float16)b.w;
    half8 hi = {h0, h1, h2, h3, h4, h5, h6, h7};
    *reinterpret_cast<half8*>(&whiA[((size_t)(c >> 5) * 8 + s) * 512 +
                                    (((khh << 5) | (c & 31)) << 3)]) = hi;

    float ssq = 0.f;
    ssq = fmaf(a.x, a.x, ssq); ssq = fmaf(a.y, a.y, ssq);
    ssq = fmaf(a.z, a.z, ssq); ssq = fmaf(a.w, a.w, ssq);
    ssq = fmaf(b.x, b.x, ssq); ssq = fmaf(b.y, b.y, ssq);
    ssq = fmaf(b.z, b.z, ssq); ssq = fmaf(b.w, b.w, ssq);
    ssq += __shfl_xor(ssq, 1, 64);
    ssq += __shfl_xor(ssq, 2, 64);
    ssq += __shfl_xor(ssq, 4, 64);
    ssq += __shfl_xor(ssq, 8, 64);
    if (hg == 0) {
        int co = c & 31;
        wq2R[((c >> 5) << 5) + (((co >> 2) & 1) << 4) + ((co & 3) | ((co >> 3) << 2))]
            = 0.5f * ssq;
        sWH[t >> 4] = ssq;
    }
    __syncthreads();
    if (t == 0) {
        float mh = 0.f;
#pragma unroll
        for (int i = 0; i < 16; ++i) mh = fmaxf(mh, sWH[i]);
        whPart[blockIdx.x] = mh;
    }
}

// ---------------------------------------------------------------------------
// Fused scan (r3 base, 64 rows/block, 4 waves, grid 512) + SOFTWARE-PIPELINED
// epilogue: the min-tree/bound/collection of tile i-1 executes while tile i's
// MFMA chains are in flight (separate pipes, m114), and the wq2 C-term is
// added in the epilogue instead of C-initing the chain -- removing the
// serial ds_read + epilogue (~350 cy) from the per-body critical path.
// Cross-round evidence: per-wave serial body latency (~1400 cy vs ~300 cy of
// pipe work) is the bottleneck; TLP/LDS/ILP restructures (r4-r8) all failed.
// ---------------------------------------------------------------------------
__global__ __launch_bounds__(256, 2) void vq_fused(
        const float* __restrict__ z, const float* __restrict__ w,
        const float* __restrict__ wq2R, const ushort* __restrict__ whiA,
        const float* __restrict__ whPart,
        float* __restrict__ out_zq, float* __restrict__ out_idx,
        float* __restrict__ out_loss) {
    __shared__ unsigned smin[64];
    __shared__ int rowcnt[64];
    __shared__ int rowovf[64];
    __shared__ int rowlist[64 * CAPR];
    __shared__ float swh[4];
    __shared__ int fb[64];
    __shared__ float lred[4];
    __shared__ __align__(16) float swq[KCODES];   // 16 KB wq2R copy

    const int t = threadIdx.x;
    const int lane = t & 63, wid = t >> 6;
    const int n = lane & 31, kh = lane >> 5;
    const int rowBase = blockIdx.x * 64;

    // codebook max ||w||^2 partial reduce (256 partials from prep)
    float wp = whPart[t];
#pragma unroll
    for (int off = 1; off < 64; off <<= 1) wp = fmaxf(wp, __shfl_xor(wp, off, 64));
    if (lane == 0) swh[wid] = wp;
    if (t < 64) { smin[t] = 0xFFFFFFFFu; rowcnt[t] = 0; rowovf[t] = 0; }

    // stage wq2R into LDS (epilogue wq2 reads become broadcast ds_reads)
    {
        const float4* g4 = reinterpret_cast<const float4*>(wq2R);
        float4* s4 = reinterpret_cast<float4*>(swq);
#pragma unroll
        for (int i = 0; i < 4; ++i) s4[i * 256 + t] = g4[i * 256 + t];
    }

    // ---- stage z: NEGATED hi fp16 B-frags for rows n and n+32 + norms ----
    half8 zbA[8], zbB[8];
    float zn2A = 0.f, zl2A = 0.f, zn2B = 0.f, zl2B = 0.f;
    {
        const float* zr = z + (size_t)(rowBase + n) * HH + (kh << 3);
#pragma unroll
        for (int s = 0; s < 8; ++s) {
            float4 a = *reinterpret_cast<const float4*>(zr + (s << 4));
            float4 b = *reinterpret_cast<const float4*>(zr + (s << 4) + 4);
            _Float16 h0=(_Float16)a.x, h1=(_Float16)a.y, h2=(_Float16)a.z, h3=(_Float16)a.w;
            _Float16 h4=(_Float16)b.x, h5=(_Float16)b.y, h6=(_Float16)b.z, h7=(_Float16)b.w;
            zbA[s] = (half8){-h0, -h1, -h2, -h3, -h4, -h5, -h6, -h7};
            zn2A = fmaf(a.x,a.x,zn2A); zn2A = fmaf(a.y,a.y,zn2A);
            zn2A = fmaf(a.z,a.z,zn2A); zn2A = fmaf(a.w,a.w,zn2A);
            zn2A = fmaf(b.x,b.x,zn2A); zn2A = fmaf(b.y,b.y,zn2A);
            zn2A = fmaf(b.z,b.z,zn2A); zn2A = fmaf(b.w,b.w,zn2A);
            float l0=a.x-(float)h0, l1=a.y-(float)h1, l2=a.z-(float)h2, l3=a.w-(float)h3;
            float l4=b.x-(float)h4, l5=b.y-(float)h5, l6=b.z-(float)h6, l7=b.w-(float)h7;
            zl2A = fmaf(l0,l0,zl2A); zl2A = fmaf(l1,l1,zl2A);
            zl2A = fmaf(l2,l2,zl2A); zl2A = fmaf(l3,l3,zl2A);
            zl2A = fmaf(l4,l4,zl2A); zl2A = fmaf(l5,l5,zl2A);
            zl2A = fmaf(l6,l6,zl2A); zl2A = fmaf(l7,l7,zl2A);
        }
        const float* zr2 = z + (size_t)(rowBase + 32 + n) * HH + (kh << 3);
#pragma unroll
        for (int s = 0; s < 8; ++s) {
            float4 a = *reinterpret_cast<const float4*>(zr2 + (s << 4));
            float4 b = *reinterpret_cast<const float4*>(zr2 + (s << 4) + 4);
            _Float16 h0=(_Float16)a.x, h1=(_Float16)a.y, h2=(_Float16)a.z, h3=(_Float16)a.w;
            _Float16 h4=(_Float16)b.x, h5=(_Float16)b.y, h6=(_Float16)b.z, h7=(_Float16)b.w;
            zbB[s] = (half8){-h0, -h1, -h2, -h3, -h4, -h5, -h6, -h7};
            zn2B = fmaf(a.x,a.x,zn2B); zn2B = fmaf(a.y,a.y,zn2B);
            zn2B = fmaf(a.z,a.z,zn2B); zn2B = fmaf(a.w,a.w,zn2B);
            zn2B = fmaf(b.x,b.x,zn2B); zn2B = fmaf(b.y,b.y,zn2B);
            zn2B = fmaf(b.z,b.z,zn2B); zn2B = fmaf(b.w,b.w,zn2B);
            float l0=a.x-(float)h0, l1=a.y-(float)h1, l2=a.z-(float)h2, l3=a.w-(float)h3;
            float l4=b.x-(float)h4, l5=b.y-(float)h5, l6=b.z-(float)h6, l7=b.w-(float)h7;
            zl2B = fmaf(l0,l0,zl2B); zl2B = fmaf(l1,l1,zl2B);
            zl2B = fmaf(l2,l2,zl2B); zl2B = fmaf(l3,l3,zl2B);
            zl2B = fmaf(l4,l4,zl2B); zl2B = fmaf(l5,l5,zl2B);
            zl2B = fmaf(l6,l6,zl2B); zl2B = fmaf(l7,l7,zl2B);
        }
        zn2A += __shfl_xor(zn2A, 32, 64);
        zl2A += __shfl_xor(zl2A, 32, 64);
        zn2B += __shfl_xor(zn2B, 32, 64);
        zl2B += __shfl_xor(zl2B, 32, 64);
    }
    __syncthreads();   // smin/cnt init + swh + swq visible

    // rigorous window: |d/2_true - est| <= E; accept if est < runmin + thrw,
    // thrw > 2E  =>  true argmin always collected; non-collected strictly
    // worse. (late wq2-add changes summation order by a few ulps -- covered
    // by the 1.01x / +4e-3 slack terms, and guarded by the exact re-eval.)
    float WH = sqrtf(fmaxf(fmaxf(swh[0], swh[1]), fmaxf(swh[2], swh[3])));
    float thrwA, thrwB;
    {
        float znr = sqrtf(zn2A), zlr = sqrtf(zl2A);
        float E = zlr * WH * 1.01f + (znr + zlr) * (WH * 4.8828125e-4f + 1e-6f) + 4e-3f;
        thrwA = 2.0f * E * 1.05f + 0.01f;
        float znr2 = sqrtf(zn2B), zlr2 = sqrtf(zl2B);
        float E2 = zlr2 * WH * 1.01f + (znr2 + zlr2) * (WH * 4.8828125e-4f + 1e-6f) + 4e-3f;
        thrwB = 2.0f * E2 * 1.05f + 0.01f;
    }

    const half8* A8 = reinterpret_cast<const half8*>(whiA);
    const int cb0 = wid << 5;
    float m1A = FLT_MAX, m1pA = FLT_MAX, m1B = FLT_MAX, m1pB = FLT_MAX;

    half8 afA[8], afB[8];
    {
        const half8* ap = A8 + ((size_t)cb0 << 3) * 64 + lane;
#pragma unroll
        for (int p = 0; p < 8; ++p) afA[p] = ap[p * 64];
    }

    const floatx16 zac = {0.f,0.f,0.f,0.f,0.f,0.f,0.f,0.f,
                          0.f,0.f,0.f,0.f,0.f,0.f,0.f,0.f};
    floatx16 pend0, pend1;   // pending accs (tile it-1), processed under tile it

    // epilogue for a PENDING tile: est = acc + wq2 (LDS, off critical path),
    // min-tree, bound check, rare reserve-then-store collection
    auto proc = [&](int pit, int pcb, const floatx16& wqp, const floatx16& acc,
                    float& m1, float& m1pub, float thrw, int row) {
        float est[16];
#pragma unroll
        for (int r = 0; r < 16; ++r) est[r] = acc[r] + wqp[r];
        float t00=fminf(est[0],est[1]),   t01=fminf(est[2],est[3]);
        float t02=fminf(est[4],est[5]),   t03=fminf(est[6],est[7]);
        float t04=fminf(est[8],est[9]),   t05=fminf(est[10],est[11]);
        float t06=fminf(est[12],est[13]), t07=fminf(est[14],est[15]);
        float tmin = fminf(fminf(fminf(t00,t01), fminf(t02,t03)),
                           fminf(fminf(t04,t05), fminf(t06,t07)));
        m1 = fminf(m1, tmin);
        if (m1 < m1pub) { atomicMin(&smin[row], fkey(m1)); m1pub = m1; }
        // register-only pre-check: shared bound <= local bound, so a local
        // fail proves no candidate here (m1 already includes this tile)
        if (pit > 0 && tmin < m1 + thrw) {
            float sh = funkey(((volatile unsigned*)smin)[row]);
            float bound = fminf(sh, m1) + thrw;
            if (tmin < bound) {
                unsigned cm = 0;
#pragma unroll
                for (int r = 0; r < 16; ++r)
                    if (est[r] < bound) cm |= (1u << r);
                int cc = __popc(cm);
                int ix = atomicAdd(&rowcnt[row], cc);
                if (ix + cc > CAPR) rowovf[row] = 1;
#pragma unroll
                for (int r = 0; r < 16; ++r) {
                    if (cm & (1u << r)) {
                        if (ix < CAPR)
                            rowlist[row * CAPR + ix] =
                                (pcb << 5) + (r & 3) + ((r >> 2) << 3) + (kh << 2);
                        ++ix;
                    }
                }
            }
        }
    };

    auto procPair = [&](int pit) {
        const int pcb = cb0 + ((pit < 32) ? pit : 0);
        const floatx16 wqp =
            *reinterpret_cast<const floatx16*>(&swq[(pcb << 5) + (kh << 4)]);
        proc(pit, pcb, wqp, pend0, m1A, m1pA, thrwA, n);
        proc(pit, pcb, wqp, pend1, m1B, m1pB, thrwB, n + 32);
    };

    auto body = [&](int it, half8 (&cur)[8], half8 (&nxt)[8]) {
        if (it < 32) {
            const int cbn = cb0 + ((it + 1) & 31);
            const half8* ap = A8 + ((size_t)cbn << 3) * 64 + lane;
#pragma unroll
            for (int p = 0; p < 8; ++p) nxt[p] = ap[p * 64];
        }
        // zero-C chains: no ds_read on the critical path; wq2 added in proc
        floatx16 a0 = __builtin_amdgcn_mfma_f32_32x32x16_f16(cur[0], zbA[0], zac, 0, 0, 0);
        floatx16 a1 = __builtin_amdgcn_mfma_f32_32x32x16_f16(cur[0], zbB[0], zac, 0, 0, 0);
#pragma unroll
        for (int s = 1; s < 8; ++s) {
            a0 = __builtin_amdgcn_mfma_f32_32x32x16_f16(cur[s], zbA[s], a0, 0, 0, 0);
            a1 = __builtin_amdgcn_mfma_f32_32x32x16_f16(cur[s], zbB[s], a1, 0, 0, 0);
        }
        // process PREVIOUS tile's accs while this tile's MFMAs are in flight
        if (it > 0) procPair(it - 1);
        pend0 = a0; pend1 = a1;
    };

#pragma unroll 1
    for (int itp = 0; itp < 16; ++itp) {
        body(2 * itp,     afA, afB);
        body(2 * itp + 1, afB, afA);
    }
    body(32, afA, afB);   // re-pass tile 0 (warm bound)
    procPair(32);         // drain the last pending (tile 0, collect=true)
    __syncthreads();

    // ---- exact fp32 eval of candidates (4 threads per row, 64 rows) ----
    {
        const int erow = t >> 2, eq = t & 3;
        int cnt = rowcnt[erow];
        bool ovf = (rowovf[erow] != 0) || (cnt > CAPR) || (cnt == 0);
        if (cnt > CAPR) cnt = CAPR;
        if (ovf) {
            if (eq == 0) rowovf[erow] = 1;
        } else {
            const float* zs = z + (size_t)(rowBase + erow) * HH + (eq << 5);
            float4 z0 = *reinterpret_cast<const float4*>(zs);
            float4 z1 = *reinterpret_cast<const float4*>(zs + 4);
            float4 z2 = *reinterpret_cast<const float4*>(zs + 8);
            float4 z3 = *reinterpret_cast<const float4*>(zs + 12);
            float4 z4v = *reinterpret_cast<const float4*>(zs + 16);
            float4 z5 = *reinterpret_cast<const float4*>(zs + 20);
            float4 z6 = *reinterpret_cast<const float4*>(zs + 24);
            float4 z7 = *reinterpret_cast<const float4*>(zs + 28);
            float bd = FLT_MAX; int bc = 0x7fffffff;
            for (int j = 0; j < cnt; ++j) {
                int c = rowlist[erow * CAPR + j];
                const float* wr = w + (size_t)c * HH + (eq << 5);
                float4 w0 = *reinterpret_cast<const float4*>(wr);
                float4 w1 = *reinterpret_cast<const float4*>(wr + 4);
                float4 w2 = *reinterpret_cast<const float4*>(wr + 8);
                float4 w3 = *reinterpret_cast<const float4*>(wr + 12);
                float4 w4 = *reinterpret_cast<const float4*>(wr + 16);
                float4 w5 = *reinterpret_cast<const float4*>(wr + 20);
                float4 w6 = *reinterpret_cast<const float4*>(wr + 24);
                float4 w7 = *reinterpret_cast<const float4*>(wr + 28);
                float dot = 0.f;
                dot = fmaf(z0.x,w0.x,dot); dot = fmaf(z0.y,w0.y,dot);
                dot = fmaf(z0.z,w0.z,dot); dot = fmaf(z0.w,w0.w,dot);
                dot = fmaf(z1.x,w1.x,dot); dot = fmaf(z1.y,w1.y,dot);
                dot = fmaf(z1.z,w1.z,dot); dot = fmaf(z1.w,w1.w,dot);
                dot = fmaf(z2.x,w2.x,dot); dot = fmaf(z2.y,w2.y,dot);
                dot = fmaf(z2.z,w2.z,dot); dot = fmaf(z2.w,w2.w,dot);
                dot = fmaf(z3.x,w3.x,dot); dot = fmaf(z3.y,w3.y,dot);
                dot = fmaf(z3.z,w3.z,dot); dot = fmaf(z3.w,w3.w,dot);
                dot = fmaf(z4v.x,w4.x,dot); dot = fmaf(z4v.y,w4.y,dot);
                dot = fmaf(z4v.z,w4.z,dot); dot = fmaf(z4v.w,w4.w,dot);
                dot = fmaf(z5.x,w5.x,dot); dot = fmaf(z5.y,w5.y,dot);
                dot = fmaf(z5.z,w5.z,dot); dot = fmaf(z5.w,w5.w,dot);
                dot = fmaf(z6.x,w6.x,dot); dot = fmaf(z6.y,w6.y,dot);
                dot = fmaf(z6.z,w6.z,dot); dot = fmaf(z6.w,w6.w,dot);
                dot = fmaf(z7.x,w7.x,dot); dot = fmaf(z7.y,w7.y,dot);
                dot = fmaf(z7.z,w7.z,dot); dot = fmaf(z7.w,w7.w,dot);
                dot += __shfl_xor(dot, 1, 64);
                dot += __shfl_xor(dot, 2, 64);
                int co = c & 31;
                float wq2v = swq[((c >> 5) << 5) + (((co >> 2) & 1) << 4)
                                 + ((co & 3) | ((co >> 3) << 2))];
                float d2 = wq2v - dot;
                if (d2 < bd || (d2 == bd && c < bc)) { bd = d2; bc = c; }
            }
            if (eq == 0) { fb[erow] = bc; out_idx[rowBase + erow] = (float)bc; }
        }
    }
    __syncthreads();

    // ---- rigorous fallback: full exact scan for overflow rows (~never),
    // rows distributed across the 4 waves ----
    for (int rr = wid; rr < 64; rr += 4) {
        if (rowovf[rr] == 0) continue;
        const float* zrow = z + (size_t)(rowBase + rr) * HH;
        float bd = FLT_MAX; int bc = 0x7fffffff;
        for (int kq = 0; kq < 64; ++kq) {
            int c = (kq << 6) + lane;
            const float* wr = w + (size_t)c * HH;
            float dot = 0.f;
            for (int h4 = 0; h4 < 32; ++h4) {
                float4 wv = *reinterpret_cast<const float4*>(wr + (h4 << 2));
                float4 zv = *reinterpret_cast<const float4*>(zrow + (h4 << 2));
                dot = fmaf(zv.x,wv.x,dot); dot = fmaf(zv.y,wv.y,dot);
                dot = fmaf(zv.z,wv.z,dot); dot = fmaf(zv.w,wv.w,dot);
            }
            int co = c & 31;
            float wq2v = swq[((c >> 5) << 5) + (((co >> 2) & 1) << 4)
                             + ((co & 3) | ((co >> 3) << 2))];
            float d2 = wq2v - dot;
            if (d2 < bd || (d2 == bd && c < bc)) { bd = d2; bc = c; }
        }
#pragma unroll
        for (int off = 1; off < 64; off <<= 1) {
            float od = __shfl_xor(bd, off, 64);
            int oc = __shfl_xor(bc, off, 64);
            if (od < bd || (od == bd && oc < bc)) { bd = od; bc = oc; }
        }
        if (lane == 0) { fb[rr] = bc; out_idx[rowBase + rr] = (float)bc; }
    }
    __syncthreads();

    // ---- zq gather + loss (proven epilogue) ----
    const float4* z4 = reinterpret_cast<const float4*>(z);
    float lsum = 0.f;
#pragma unroll
    for (int i = 0; i < 8; ++i) {
        int g = i * 256 + t;
        int r = g >> 5, f4 = g & 31;
        int code = fb[r];
        float4 wv = *reinterpret_cast<const float4*>(w + (size_t)code * HH + (f4 << 2));
        float4 zv = z4[(size_t)(rowBase + r) * 32 + f4];
        float dx = wv.x - zv.x, dy = wv.y - zv.y, dz = wv.z - zv.z, dw = wv.w - zv.w;
        lsum = fmaf(dx, dx, lsum); lsum = fmaf(dy, dy, lsum);
        lsum = fmaf(dz, dz, lsum); lsum = fmaf(dw, dw, lsum);
        *reinterpret_cast<float4*>(out_zq + (size_t)(rowBase + r) * HH + (f4 << 2)) = wv;
    }
#pragma unroll
    for (int off = 1; off < 64; off <<= 1) lsum += __shfl_xor(lsum, off, 64);
    if (lane == 0) lred[wid] = lsum;
    __syncthreads();
    if (t == 0) {
        float total = lred[0] + lred[1] + lred[2] + lred[3];
        atomicAdd(out_loss, total * (1.25f / 4194304.0f));  // (0.25+1)*mean, N*H
    }
}

// ---------------- fallback path (Round-2 kernels, proven) -------------------
__device__ __forceinline__ int plane_off_fb(int r, int hu) {
    return ((hu << 6) | (r ^ (hu & 7))) << 3;
}

__global__ __launch_bounds__(256) void vq_prep_fb(const float* __restrict__ w,
                                                  float* __restrict__ wsq,
                                                  float* __restrict__ loss_slot) {
    int c = blockIdx.x * 256 + threadIdx.x;
    if (c == 0) loss_slot[0] = 0.0f;
    if (c < KCODES) {
        const float4* row = reinterpret_cast<const float4*>(w + (size_t)c * HH);
        float s = 0.0f;
#pragma unroll
        for (int i = 0; i < HH / 4; ++i) {
            float4 v = row[i];
            s = fmaf(v.x, v.x, s); s = fmaf(v.y, v.y, s);
            s = fmaf(v.z, v.z, s); s = fmaf(v.w, v.w, s);
        }
        wsq[c] = s;
    }
}

__device__ __forceinline__ void stage_tile_fb(const float4* __restrict__ src4,
                                              ushort* lds, int hi_base, int lo_base,
                                              int t) {
#pragma unroll
    for (int p = 0; p < 8; ++p) {
        int g = p * 256 + t;
        int r = g >> 5, f4 = g & 31;
        float4 v = src4[g];
        _Float16 h0 = (_Float16)v.x, h1 = (_Float16)v.y,
                 h2 = (_Float16)v.z, h3 = (_Float16)v.w;
        half4_t hv = {h0, h1, h2, h3};
        half4_t lv = {(_Float16)(v.x - (float)h0), (_Float16)(v.y - (float)h1),
                      (_Float16)(v.z - (float)h2), (_Float16)(v.w - (float)h3)};
        int off = plane_off_fb(r, f4 >> 1) + ((f4 & 1) << 2);
        *reinterpret_cast<half4_t*>(&lds[hi_base + off]) = hv;
        *reinterpret_cast<half4_t*>(&lds[lo_base + off]) = lv;
    }
}

__global__ __launch_bounds__(256, 2) void vq_main_fb(const float* __restrict__ z,
                                                     const float* __restrict__ w,
                                                     const float* __restrict__ wsq,
                                                     float* __restrict__ out_zq,
                                                     float* __restrict__ out_idx,
                                                     float* __restrict__ out_loss) {
    __shared__ __align__(16) ushort lds[32768];
    const int t = threadIdx.x, lane = t & 63, wid = t >> 6;
    const int q = lane >> 4, m15 = lane & 15;
    const int wrow = (wid >> 1) << 5, wcol = (wid & 1) << 5;
    const int rowBase = blockIdx.x * 64;

    stage_tile_fb(reinterpret_cast<const float4*>(z + (size_t)rowBase * HH), lds, 0, 8192, t);

    float best[2][4]; int bidx[2][4];
#pragma unroll
    for (int mt = 0; mt < 2; ++mt)
#pragma unroll
        for (int rg = 0; rg < 4; ++rg) { best[mt][rg] = FLT_MAX; bidx[mt][rg] = 0; }

    const int ar0 = wrow + m15, bn0 = wcol + m15;

    for (int k0 = 0; k0 < KCODES; k0 += 64) {
        __syncthreads();
        stage_tile_fb(reinterpret_cast<const float4*>(w + (size_t)k0 * HH), lds, 16384, 24576, t);
        __syncthreads();
        floatx4 acc[2][2];
#pragma unroll
        for (int mt = 0; mt < 2; ++mt)
#pragma unroll
            for (int nt = 0; nt < 2; ++nt) acc[mt][nt] = (floatx4){0.f, 0.f, 0.f, 0.f};
#pragma unroll
        for (int c = 0; c < 4; ++c) {
            const int hu = (c << 2) + q;
            half8 zh0 = *reinterpret_cast<half8*>(&lds[plane_off_fb(ar0, hu)]);
            half8 zh1 = *reinterpret_cast<half8*>(&lds[plane_off_fb(ar0 + 16, hu)]);
            half8 zl0 = *reinterpret_cast<half8*>(&lds[8192 + plane_off_fb(ar0, hu)]);
            half8 zl1 = *reinterpret_cast<half8*>(&lds[8192 + plane_off_fb(ar0 + 16, hu)]);
            half8 wh0 = *reinterpret_cast<half8*>(&lds[16384 + plane_off_fb(bn0, hu)]);
            half8 wh1 = *reinterpret_cast<half8*>(&lds[16384 + plane_off_fb(bn0 + 16, hu)]);
            half8 wl0 = *reinterpret_cast<half8*>(&lds[24576 + plane_off_fb(bn0, hu)]);
            half8 wl1 = *reinterpret_cast<half8*>(&lds[24576 + plane_off_fb(bn0 + 16, hu)]);
            acc[0][0] = __builtin_amdgcn_mfma_f32_16x16x32_f16(zh0, wh0, acc[0][0], 0, 0, 0);
            acc[0][1] = __builtin_amdgcn_mfma_f32_16x16x32_f16(zh0, wh1, acc[0][1], 0, 0, 0);
            acc[1][0] = __builtin_amdgcn_mfma_f32_16x16x32_f16(zh1, wh0, acc[1][0], 0, 0, 0);
            acc[1][1] = __builtin_amdgcn_mfma_f32_16x16x32_f16(zh1, wh1, acc[1][1], 0, 0, 0);
            acc[0][0] = __builtin_amdgcn_mfma_f32_16x16x32_f16(zh0, wl0, acc[0][0], 0, 0, 0);
            acc[0][1] = __builtin_amdgcn_mfma_f32_16x16x32_f16(zh0, wl1, acc[0][1], 0, 0, 0);
            acc[1][0] = __builtin_amdgcn_mfma_f32_16x16x32_f16(zh1, wl0, acc[1][0], 0, 0, 0);
            acc[1][1] = __builtin_amdgcn_mfma_f32_16x16x32_f16(zh1, wl1, acc[1][1], 0, 0, 0);
            acc[0][0] = __builtin_amdgcn_mfma_f32_16x16x32_f16(zl0, wh0, acc[0][0], 0, 0, 0);
            acc[0][1] = __builtin_amdgcn_mfma_f32_16x16x32_f16(zl0, wh1, acc[0][1], 0, 0, 0);
            acc[1][0] = __builtin_amdgcn_mfma_f32_16x16x32_f16(zl1, wh0, acc[1][0], 0, 0, 0);
            acc[1][1] = __builtin_amdgcn_mfma_f32_16x16x32_f16(zl1, wh1, acc[1][1], 0, 0, 0);
        }
        float wq0 = wsq[k0 + bn0], wq1 = wsq[k0 + bn0 + 16];
#pragma unroll
        for (int mt = 0; mt < 2; ++mt)
#pragma unroll
            for (int nt = 0; nt < 2; ++nt) {
                int code = k0 + wcol + (nt << 4) + m15;
                float wqv = nt ? wq1 : wq0;
#pragma unroll
                for (int rg = 0; rg < 4; ++rg) {
                    float s = fmaf(-2.0f, acc[mt][nt][rg], wqv);
                    if (s < best[mt][rg]) { best[mt][rg] = s; bidx[mt][rg] = code; }
                }
            }
    }
#pragma unroll
    for (int off = 1; off < 16; off <<= 1)
#pragma unroll
        for (int mt = 0; mt < 2; ++mt)
#pragma unroll
            for (int rg = 0; rg < 4; ++rg) {
                float os = __shfl_xor(best[mt][rg], off, 64);
                int   oi = __shfl_xor(bidx[mt][rg], off, 64);
                if (os < best[mt][rg] || (os == best[mt][rg] && oi < bidx[mt][rg])) {
                    best[mt][rg] = os; bidx[mt][rg] = oi;
                }
            }
    float* epmin = reinterpret_cast<float*>(lds);
    int*   epidx = reinterpret_cast<int*>(reinterpret_cast<char*>(lds) + 512);
    int*   fbidx = reinterpret_cast<int*>(reinterpret_cast<char*>(lds) + 1024);
    float* lredf = reinterpret_cast<float*>(reinterpret_cast<char*>(lds) + 1280);
    __syncthreads();
    if (m15 == 0) {
        int g = wid & 1;
#pragma unroll
        for (int mt = 0; mt < 2; ++mt)
#pragma unroll
            for (int rg = 0; rg < 4; ++rg) {
                int row = wrow + (mt << 4) + (q << 2) + rg;
                epmin[g * 64 + row] = best[mt][rg];
                epidx[g * 64 + row] = bidx[mt][rg];
            }
    }
    __syncthreads();
    if (t < 64) {
        float s0 = epmin[t], s1 = epmin[64 + t];
        int   i0 = epidx[t], i1 = epidx[64 + t];
        int   fi = (s1 < s0 || (s1 == s0 && i1 < i0)) ? i1 : i0;
        fbidx[t] = fi;
        out_idx[rowBase + t] = (float)fi;
    }
    __syncthreads();
    const float4* z4 = reinterpret_cast<const float4*>(z);
    float lsum = 0.0f;
#pragma unroll
    for (int i = 0; i < 8; ++i) {
        int g = i * 256 + t;
        int r = g >> 5, f4 = g & 31;
        int code = fbidx[r];
        float4 wv = *reinterpret_cast<const float4*>(w + (size_t)code * HH + (f4 << 2));
        float4 zv = z4[(size_t)(rowBase + r) * 32 + f4];
        float dx = wv.x - zv.x, dy = wv.y - zv.y, dz = wv.z - zv.z, dw = wv.w - zv.w;
        lsum = fmaf(dx, dx, lsum); lsum = fmaf(dy, dy, lsum);
        lsum = fmaf(dz, dz, lsum); lsum = fmaf(dw, dw, lsum);
        *reinterpret_cast<float4*>(out_zq + (size_t)(rowBase + r) * HH + (f4 << 2)) = wv;
    }
#pragma unroll
    for (int off = 1; off < 64; off <<= 1) lsum += __shfl_xor(lsum, off, 64);
    if (lane == 0) lredf[wid] = lsum;
    __syncthreads();
    if (t == 0)
        atomicAdd(out_loss, (lredf[0] + lredf[1] + lredf[2] + lredf[3]) * (1.25f / 4194304.0f));
}

extern "C" void kernel_launch(void* const* d_in, const int* in_sizes, int n_in,
                              void* d_out, int out_size, void* d_ws, size_t ws_size,
                              hipStream_t stream) {
    (void)in_sizes; (void)n_in; (void)out_size;
    const float* z = (const float*)d_in[0];
    const float* w = (const float*)d_in[1];
    float* out      = (float*)d_out;
    float* out_zq   = out;
    float* out_idx  = out + (size_t)NROWS * HH;
    float* out_loss = out_idx + NROWS;

    char* wsb = (char*)d_ws;
    float*  wq2R   = (float*)(wsb + 0);        // 16 KB
    float*  whPart = (float*)(wsb + 16384);    // 1 KB
    ushort* whiA   = (ushort*)(wsb + 17408);   // 1 MB f16 codes, A-frag order
    const size_t WS_NEED = 17408 + (size_t)KCODES * HH * 2;

    if (ws_size >= WS_NEED) {
        vq_prep<<<256, 256, 0, stream>>>(w, wq2R, whiA, whPart, out_loss);
        vq_fused<<<NROWS / 64, 256, 0, stream>>>(z, w, wq2R, whiA, whPart,
                                                 out_zq, out_idx, out_loss);
    } else {
        float* wsq = (float*)d_ws;
        vq_prep_fb<<<KCODES / 256, 256, 0, stream>>>(w, wsq, out_loss);
        vq_main_fb<<<NROWS / 64, 256, 0, stream>>>(z, w, wsq, out_zq, out_idx, out_loss);
    }
}